// Round 11
// baseline (384.437 us; speedup 1.0000x reference)
//
#include <hip/hip_runtime.h>
#include <cstddef>

#define H 128
#define W 128
#define P_THRESH 20

typedef float f4u __attribute__((ext_vector_type(4), aligned(4)));
typedef int   i4u __attribute__((ext_vector_type(4), aligned(4)));
typedef float nf2 __attribute__((ext_vector_type(2)));

// r9 champion + 2-slice ILP batching.
//   block = 4 rows x 128 cols x TWO independent slices; thread = 1 row x 2 cols
//   per slice. All 6 input f4u loads issue at thread start; the single pack
//   phase covers both slices (384 items); after the barrier, slice 0 then
//   slice 1 are computed sequentially -- slice 1's loads have been in flight
//   the whole time, so its compute adds pure VALU with no memory wait.
//   Per-wave duty ~2x at constant wave lifetime; register working set stays
//   transient (one slice at a time).
//   Masks: byte = dir if prob<=20 AND target px in-image, else 8; guard word
//   + per-row pad => edge-case-free extraction (2 LDS words + funnel shift).
__global__ __launch_bounds__(256, 8)
void brown_kernel(const float* __restrict__ inp,
                  const int*  __restrict__ dirp,
                  const int*  __restrict__ prb,
                  float* __restrict__ out)
{
    // per slice: [0]=guard, rows r6=0..5 at [1+33*r6+w], w=32 = pad (all 8s)
    __shared__ unsigned int s_mk[2 * 199];   // 1592 B

    const int tid   = threadIdx.x;
    const int bid   = blockIdx.x;
    const int spair = bid >> 5;              // slice pair 0..1023
    const int r0    = (bid & 31) << 2;
    const size_t base0 = (size_t)(2 * spair) * (size_t)(H * W);
    const size_t base1 = base0 + (size_t)(H * W);

    const int lane = tid & 63;
    const int row  = tid >> 6;               // 0..3 (wave-uniform)
    const int gi   = r0 + row;
    const int j0   = lane << 1;

    // ---- all input loads first: in flight across pack + barrier + slice0 ----
    const int cl = (lane == 0) ? 0 : ((lane == 63) ? (W - 4) : (j0 - 1));
    const int rT = (gi == 0) ? 1 : gi - 1;           // reflect rows for avg
    const int rB = (gi == H - 1) ? H - 2 : gi + 1;
    const f4u iT0 = *(const f4u*)(inp + base0 + (size_t)rT * W + cl);
    const f4u iM0 = *(const f4u*)(inp + base0 + (size_t)gi * W + cl);
    const f4u iB0 = *(const f4u*)(inp + base0 + (size_t)rB * W + cl);
    const f4u iT1 = *(const f4u*)(inp + base1 + (size_t)rT * W + cl);
    const f4u iM1 = *(const f4u*)(inp + base1 + (size_t)gi * W + cl);
    const f4u iB1 = *(const f4u*)(inp + base1 + (size_t)rB * W + cl);

    // ---- pack phase: 2 slices x 6 rows x 32 words = 384 items ----
    #pragma unroll
    for (int it = 0; it < 2; ++it) {
        const int idx = it * 256 + tid;
        if (idx < 384) {
            const int s  = (idx >= 192);
            const int k  = idx - s * 192;
            const int r6 = k >> 5;           // LDS mask row 0..5
            const int w  = k & 31;           // word = 4 cols
            const int gr = r0 + r6 - 1;      // image row
            const size_t bs = s ? base1 : base0;
            unsigned m;
            if ((unsigned)gr < (unsigned)H) {
                const i4u dv = *(const i4u*)(dirp + bs + (size_t)gr * W + 4 * w);
                const i4u pv = *(const i4u*)(prb  + bs + (size_t)gr * W + 4 * w);
                const unsigned a = (pv.x <= P_THRESH) ? (unsigned)dv.x : 8u;
                const unsigned b = (pv.y <= P_THRESH) ? (unsigned)dv.y : 8u;
                const unsigned c = (pv.z <= P_THRESH) ? (unsigned)dv.z : 8u;
                const unsigned e = (pv.w <= P_THRESH) ? (unsigned)dv.w : 8u;
                m = a | (b << 8) | (c << 16) | (e << 24);
                if (gr == 0) {               // top row: d in {0,1,2} writes up -> OOB
                    unsigned mm = 0;
                    #pragma unroll
                    for (int i2 = 0; i2 < 4; ++i2) {
                        unsigned bb = (m >> (8 * i2)) & 255u;
                        bb = (bb <= 2u) ? 8u : bb;
                        mm |= bb << (8 * i2);
                    }
                    m = mm;
                } else if (gr == H - 1) {    // bottom row: d in {6,7} writes down -> OOB
                    unsigned mm = 0;
                    #pragma unroll
                    for (int i2 = 0; i2 < 4; ++i2) {
                        unsigned bb = (m >> (8 * i2)) & 255u;
                        bb = (bb >= 6u) ? 8u : bb;
                        mm |= bb << (8 * i2);
                    }
                    m = mm;
                }
                if (w == 0) {                // image col 0: d in {0,3,6} (dj=-1) -> OOB
                    const unsigned b0 = m & 255u;
                    if ((0x49u >> b0) & 1u) m = (m & ~255u) | 8u;
                }
                if (w == 31) {               // image col 127: d in {2,5} (dj=+1) -> OOB
                    const unsigned b3 = m >> 24;
                    if ((0x24u >> b3) & 1u) m = (m & 0x00FFFFFFu) | (8u << 24);
                }
            } else {
                m = 0x08080808u;             // out-of-image rows never source writes
            }
            s_mk[s * 199 + 1 + 33 * r6 + w] = m;
            if (w == 31) s_mk[s * 199 + 1 + 33 * r6 + 32] = 0x08080808u;  // row pad
        }
    }
    if (tid < 2) s_mk[tid * 199] = 0x08080808u;   // guards
    __syncthreads();

    // ---- shared helpers ----
    const bool e0 = (lane == 0), e63 = (lane == 63), eE = e0 | e63;
    auto fixrow = [&](f4u i, float v[4]) {
        // window cols {j0-1, j0, j0+1, j0+2}; lane 0 loaded {0..3} wants
        // {1,0,1,2}; lane 63 loaded {124..127} wants {125,126,127,126}.
        v[0] = eE ? i.y : i.x;
        v[1] = e0 ? i.x : (e63 ? i.z : i.y);
        v[2] = e0 ? i.y : (e63 ? i.w : i.z);
        v[3] = eE ? i.z : i.w;
    };
    // byte addr of col j0-1 in row rm (incl. 4B guard) = 132*rm + j0 + 3
    auto mwin = [&](int s, int dr) -> unsigned {
        const int addr = 132 * (row + dr) + (j0 + 3);
        const unsigned w0 = s_mk[s * 199 + (addr >> 2)];
        const unsigned w1 = s_mk[s * 199 + (addr >> 2) + 1];
        const int sh = 8 * (addr & 3);       // lane even: 24, odd: 8 (never 0)
        return (w0 >> sh) | (w1 << (32 - sh));
    };
    auto crow = [&](unsigned mT, unsigned mM, unsigned mB,
                    const float vT[4], const float vM[4], const float vBo[4]) -> nf2 {
        float cs[4];
        #pragma unroll
        for (int w = 0; w < 4; ++w) cs[w] = vT[w] + vM[w] + vBo[w];
        nf2 res;
        #pragma unroll
        for (int p = 0; p < 2; ++p) {
            const float avg = (cs[p] + cs[p + 1] + cs[p + 2]) * (1.0f / 9.0f);
            const unsigned wT = mT >> (8 * p);   // b0=m[p] b1=m[p+1] b2=m[p+2]
            const unsigned wM = mM >> (8 * p);
            const unsigned wB = mB >> (8 * p);

            float val = vM[p + 1];   // input[i][j]
            int dl = -1;             // direction of last A-write
            // A-writes ascending d; source offset = (-di,-dj)
            if (((wB >> 16) & 255u) == 0u) { val = vBo[p + 2]; dl = 0; }
            if (((wB >>  8) & 255u) == 1u) { val = vBo[p + 1]; dl = 1; }
            if (( wB        & 255u) == 2u) { val = vBo[p];     dl = 2; }
            if (((wM >> 16) & 255u) == 3u) { val = vM[p + 2];  dl = 3; }
            if (( wM        & 255u) == 5u) { val = vM[p];      dl = 5; }
            if (((wT >> 16) & 255u) == 6u) { val = vT[p + 2];  dl = 6; }
            if (((wT >>  8) & 255u) == 7u) { val = vT[p + 1];  dl = 7; }

            // B-write (avg): borders pre-folded -> just active + priority
            const int msel = (int)((wM >> 8) & 255u);
            if ((msel < 8) & (msel >= dl)) val = avg;
            res[p] = val;
        }
        return res;
    };

    // ---- slice 0 (loads arrived long ago; pure VALU) ----
    {
        float vT[4], vM[4], vB[4];
        fixrow(iT0, vT); fixrow(iM0, vM); fixrow(iB0, vB);
        const nf2 r = crow(mwin(0, 0), mwin(0, 1), mwin(0, 2), vT, vM, vB);
        *(nf2*)(out + base0 + (size_t)gi * W + j0) = r;
    }
    // ---- slice 1 (independent work: no memory wait here either) ----
    {
        float vT[4], vM[4], vB[4];
        fixrow(iT1, vT); fixrow(iM1, vM); fixrow(iB1, vB);
        const nf2 r = crow(mwin(1, 0), mwin(1, 1), mwin(1, 2), vT, vM, vB);
        *(nf2*)(out + base1 + (size_t)gi * W + j0) = r;
    }
}

extern "C" void kernel_launch(void* const* d_in, const int* in_sizes, int n_in,
                              void* d_out, int out_size, void* d_ws, size_t ws_size,
                              hipStream_t stream) {
    const float* inp  = (const float*)d_in[0];
    const int*   dirp = (const int*)d_in[1];
    const int*   prb  = (const int*)d_in[2];
    float* out = (float*)d_out;

    const int slices = in_sizes[0] / (H * W);   // 2048
    const int grid = (slices >> 1) * 32;        // 2 slices x 4 rows per block
    brown_kernel<<<grid, 256, 0, stream>>>(inp, dirp, prb, out);
}

// Round 12
// 380.554 us; speedup vs baseline: 1.0102x; 1.0102x over previous
//
#include <hip/hip_runtime.h>
#include <cstddef>

#define H 128
#define W 128
#define P_THRESH 20

typedef float f4u __attribute__((ext_vector_type(4), aligned(4)));
typedef int   i4u __attribute__((ext_vector_type(4), aligned(4)));
typedef float nf2 __attribute__((ext_vector_type(2)));

// Barrier-free dedup: wave = 2 rows x 128 cols (4 px/lane), zero LDS/sync.
//   The wave needs mask rows pr-1..pr+2 = 4 x 32 words = 128 = 2 packs/lane:
//   lanes 0-31 pack word l of rows {pr-1, pr+1}; lanes 32-63 pack word l-32 of
//   rows {pr, pr+2}. Consumers get their 4-byte windows via 8 __shfl + 4
//   funnel shifts (flat 2-level dataflow, no serial chain, no barrier).
//   Border writes folded at pack time (byte = dir if prob<=20 AND target px
//   in-image, else 8): row folds are wave-uniform branches (only pr=0/126
//   waves pay); col folds are 2-lane micro-bodies.
//   Input: 4 unaligned f4u row loads (halo via load window, L1 absorbs
//   overlap); 6 cndmask/row edge fix; shared middle column sums.
__global__ __launch_bounds__(256, 6)
void brown_kernel(const float* __restrict__ inp,
                  const int*  __restrict__ dirp,
                  const int*  __restrict__ prb,
                  float* __restrict__ out)
{
    const int tid   = threadIdx.x;
    const int bid   = blockIdx.x;
    const int slice = bid >> 4;           // 16 blocks (8 rows each) per slice
    const int r0    = (bid & 15) << 3;
    const size_t base = (size_t)slice * (size_t)(H * W);

    const int lane = tid & 63;
    const int wv   = tid >> 6;            // wave 0..3
    const int pr   = r0 + (wv << 1);      // top output row (wave-uniform, even)
    const int j0   = lane << 1;           // own cols j0, j0+1
    const int w    = lane & 31;           // mask word this lane packs
    const bool hi  = lane >= 32;

    // ---- input loads: 4 rows, unaligned 16B window (cols j0-1..j0+2) ----
    const int cl = (lane == 0) ? 0 : ((lane == 63) ? (W - 4) : (j0 - 1));
    const int gA = (pr == 0) ? 1 : pr - 1;          // reflect row -1 -> 1
    const int gD = (pr == 126) ? 126 : pr + 2;      // reflect row 128 -> 126
    const float* ip = inp + base;
    const f4u iA = *(const f4u*)(ip + (size_t)gA * W + cl);
    const f4u iB = *(const f4u*)(ip + (size_t)pr * W + cl);
    const f4u iC = *(const f4u*)(ip + (size_t)(pr + 1) * W + cl);
    const f4u iD = *(const f4u*)(ip + (size_t)gD * W + cl);

    // ---- mask loads + pack: 2 (row,word) items per lane, zero waste ----
    const int grA_ = hi ? pr : pr - 1;
    const int grB_ = hi ? pr + 2 : pr + 1;
    const int grA = (grA_ < 0) ? 0 : grA_;          // clamp for safe address
    const int grB = (grB_ > H - 1) ? H - 1 : grB_;
    const i4u dvA = *(const i4u*)(dirp + base + (size_t)grA * W + 4 * w);
    const i4u pvA = *(const i4u*)(prb  + base + (size_t)grA * W + 4 * w);
    const i4u dvB = *(const i4u*)(dirp + base + (size_t)grB * W + 4 * w);
    const i4u pvB = *(const i4u*)(prb  + base + (size_t)grB * W + 4 * w);

    auto packm = [](i4u d, i4u p) -> unsigned {
        const unsigned a = (p.x <= P_THRESH) ? (unsigned)d.x : 8u;
        const unsigned b = (p.y <= P_THRESH) ? (unsigned)d.y : 8u;
        const unsigned c = (p.z <= P_THRESH) ? (unsigned)d.z : 8u;
        const unsigned e = (p.w <= P_THRESH) ? (unsigned)d.w : 8u;
        return a | (b << 8) | (c << 16) | (e << 24);
    };
    unsigned rA = packm(dvA, pvA);
    unsigned rB = packm(dvB, pvB);

    // col folds (2-lane divergent micro-bodies)
    if (w == 0) {                 // image col 0: d in {0,3,6} (dj=-1) -> OOB
        const unsigned bA = rA & 255u;
        if ((0x49u >> bA) & 1u) rA = (rA & ~255u) | 8u;
        const unsigned bB = rB & 255u;
        if ((0x49u >> bB) & 1u) rB = (rB & ~255u) | 8u;
    }
    if (w == 31) {                // image col 127: d in {2,5} (dj=+1) -> OOB
        const unsigned bA = rA >> 24;
        if ((0x24u >> bA) & 1u) rA = (rA & 0x00FFFFFFu) | (8u << 24);
        const unsigned bB = rB >> 24;
        if ((0x24u >> bB) & 1u) rB = (rB & 0x00FFFFFFu) | (8u << 24);
    }
    // row folds + OOB rows (wave-uniform: only waves pr=0 / pr=126 pay)
    if (pr == 0) {
        unsigned f = 0;           // row 0: d in {0,1,2} writes up -> OOB
        #pragma unroll
        for (int i2 = 0; i2 < 4; ++i2) {
            unsigned bb = (rA >> (8 * i2)) & 255u;
            bb = (bb <= 2u) ? 8u : bb;
            f |= bb << (8 * i2);
        }
        rA = hi ? f : 0x08080808u;       // lanes<32: row -1 never sources
    } else if (pr == 126) {
        unsigned f = 0;           // row 127: d in {6,7} writes down -> OOB
        #pragma unroll
        for (int i2 = 0; i2 < 4; ++i2) {
            unsigned bb = (rB >> (8 * i2)) & 255u;
            bb = (bb >= 6u) ? 8u : bb;
            f |= bb << (8 * i2);
        }
        rB = hi ? 0x08080808u : f;       // lanes>=32: row 128 never sources
    }

    // ---- distribute mask windows: bytes = cols {j0-1, j0, j0+1, j0+2} ----
    const int w0 = (lane == 0)  ? 0  : ((j0 - 1) >> 2);
    const int w1 = (lane == 63) ? 31 : ((j0 + 2) >> 2);
    const int sh = (lane & 1) ? 8 : 24;      // byte offset of col j0-1 in word
    auto mwin = [&](unsigned regv, int sel) -> unsigned {
        const unsigned s0 = __shfl(regv, sel + w0, 64);
        const unsigned s1 = __shfl(regv, sel + w1, 64);
        unsigned win = (s0 >> sh) | (s1 << (32 - sh));
        if (lane == 0)  win = (s0 << 8) | 8u;            // guard col -1
        if (lane == 63) win = (s0 >> 8) | 0x08000000u;   // guard col 128
        return win;
    };
    const unsigned mT = mwin(rA, 0);     // row pr-1 (lanes 0-31 hold it)
    const unsigned mM = mwin(rA, 32);    // row pr   (lanes 32-63)
    const unsigned mC = mwin(rB, 0);     // row pr+1 (lanes 0-31)
    const unsigned mB2 = mwin(rB, 32);   // row pr+2 (lanes 32-63)

    // ---- float windows: cols {j0-1, j0, j0+1, j0+2}; 6 cndmask/row fix ----
    const bool e0 = (lane == 0), e63 = (lane == 63), eE = e0 | e63;
    auto fixrow = [&](f4u i, float v[4]) {
        // lane 0 loaded {0..3} wants {1,0,1,2}; lane 63 loaded {124..127}
        // wants {125,126,127,126}; others exact.
        v[0] = eE ? i.y : i.x;
        v[1] = e0 ? i.x : (e63 ? i.z : i.y);
        v[2] = e0 ? i.y : (e63 ? i.w : i.z);
        v[3] = eE ? i.z : i.w;
    };
    float v0[4], v1[4], v2[4], v3[4];
    fixrow(iA, v0); fixrow(iB, v1); fixrow(iC, v2); fixrow(iD, v3);

    // ---- column sums (middle pair shared by both output rows) ----
    float s12[4], csT[4], csB[4];
    #pragma unroll
    for (int k = 0; k < 4; ++k) {
        s12[k] = v1[k] + v2[k];
        csT[k] = v0[k] + s12[k];
        csB[k] = s12[k] + v3[k];
    }

    // ---- cascade for one output row (2 px) ----
    auto crow = [&](unsigned mTa, unsigned mMa, unsigned mBa,
                    const float vT[4], const float vM[4], const float vBo[4],
                    const float cs[4]) -> nf2 {
        nf2 res;
        #pragma unroll
        for (int p = 0; p < 2; ++p) {
            const float avg = (cs[p] + cs[p + 1] + cs[p + 2]) * (1.0f / 9.0f);
            const unsigned wT = mTa >> (8 * p);  // b0=m[p] b1=m[p+1] b2=m[p+2]
            const unsigned wM = mMa >> (8 * p);
            const unsigned wB = mBa >> (8 * p);

            float val = vM[p + 1];   // input[i][j]
            int dl = -1;             // direction of last A-write
            // A-writes ascending d; source offset = (-di,-dj)
            if (((wB >> 16) & 255u) == 0u) { val = vBo[p + 2]; dl = 0; }
            if (((wB >>  8) & 255u) == 1u) { val = vBo[p + 1]; dl = 1; }
            if (( wB        & 255u) == 2u) { val = vBo[p];     dl = 2; }
            if (((wM >> 16) & 255u) == 3u) { val = vM[p + 2];  dl = 3; }
            if (( wM        & 255u) == 5u) { val = vM[p];      dl = 5; }
            if (((wT >> 16) & 255u) == 6u) { val = vT[p + 2];  dl = 6; }
            if (((wT >>  8) & 255u) == 7u) { val = vT[p + 1];  dl = 7; }

            // B-write (avg): borders pre-folded -> just active + priority
            const int msel = (int)((wM >> 8) & 255u);
            if ((msel < 8) & (msel >= dl)) val = avg;
            res[p] = val;
        }
        return res;
    };

    const nf2 resT = crow(mT, mM, mC,  v0, v1, v2, csT);   // row pr
    const nf2 resB = crow(mM, mC, mB2, v1, v2, v3, csB);   // row pr+1
    *(nf2*)(out + base + (size_t)pr * W + j0)       = resT;
    *(nf2*)(out + base + (size_t)(pr + 1) * W + j0) = resB;
}

extern "C" void kernel_launch(void* const* d_in, const int* in_sizes, int n_in,
                              void* d_out, int out_size, void* d_ws, size_t ws_size,
                              hipStream_t stream) {
    const float* inp  = (const float*)d_in[0];
    const int*   dirp = (const int*)d_in[1];
    const int*   prb  = (const int*)d_in[2];
    float* out = (float*)d_out;

    const int slices = in_sizes[0] / (H * W);   // 2048
    const int grid = slices * 16;               // 8 rows per block -> 32768
    brown_kernel<<<grid, 256, 0, stream>>>(inp, dirp, prb, out);
}

// Round 13
// 374.993 us; speedup vs baseline: 1.0252x; 1.0148x over previous
//
#include <hip/hip_runtime.h>
#include <cstddef>

#define H 128
#define W 128
#define P_THRESH 20

typedef float f4u __attribute__((ext_vector_type(4), aligned(4)));
typedef int   i4u __attribute__((ext_vector_type(4), aligned(4)));
typedef float nf2 __attribute__((ext_vector_type(2)));

// r9 champion with an 8-row block: 512 thr = 8 waves, thread = 1 row x 2 cols
// (identical per-thread compute path to r9). Gains vs r9 at EQUAL wave count
// (262144): mask HBM amp 1.5x -> 1.25x (10 mask rows / 8 output rows), pack
// phase 320 items over 512 threads (0.625/thr vs 0.75). LDS 1.3 KB.
//   Masks: byte = dir if prob<=20 AND target px in-image, else 8; border
//   folds at pack time; guard word + per-row pad => edge-case-free window
//   extraction (2 LDS words + funnel shift, sh in {8,24}, never 0).
//   Input: 3 unaligned f4u row loads issued before the barrier (fly across
//   it); 6 cndmask/row edge fix.
__global__ __launch_bounds__(512, 8)
void brown_kernel(const float* __restrict__ inp,
                  const int*  __restrict__ dirp,
                  const int*  __restrict__ prb,
                  float* __restrict__ out)
{
    // [0] = guard; rows lr=0..9 at [1+33*lr+w], w=32 is the 4B pad (all 8s)
    __shared__ unsigned int s_mk[331];   // 1324 B

    const int tid   = threadIdx.x;
    const int bid   = blockIdx.x;
    const int slice = bid >> 4;
    const int r0    = (bid & 15) << 3;   // 8 rows per block
    const size_t base = (size_t)slice * (size_t)(H * W);

    const int lane = tid & 63;
    const int row  = tid >> 6;           // 0..7 (wave-uniform)
    const int gi   = r0 + row;
    const int j0   = lane << 1;

    // ---- input loads first (independent of LDS, fly across the barrier) ----
    const int cl = (lane == 0) ? 0 : ((lane == 63) ? (W - 4) : (j0 - 1));
    const int rT = (gi == 0) ? 1 : gi - 1;          // reflect rows for avg
    const int rB = (gi == H - 1) ? H - 2 : gi + 1;
    const float* ip = inp + base;
    const f4u iT = *(const f4u*)(ip + (size_t)rT * W + cl);
    const f4u iM = *(const f4u*)(ip + (size_t)gi * W + cl);
    const f4u iB = *(const f4u*)(ip + (size_t)rB * W + cl);

    // ---- pack phase: 10 mask rows x 32 words = 320 items, once per block ----
    if (tid < 320) {
        const int lr = tid >> 5;        // LDS mask row 0..9
        const int w  = tid & 31;        // word = 4 cols
        const int gr = r0 + lr - 1;     // image row
        unsigned m;
        if ((unsigned)gr < (unsigned)H) {
            const i4u dv = *(const i4u*)(dirp + base + (size_t)gr * W + 4 * w);
            const i4u pv = *(const i4u*)(prb  + base + (size_t)gr * W + 4 * w);
            const unsigned a = (pv.x <= P_THRESH) ? (unsigned)dv.x : 8u;
            const unsigned b = (pv.y <= P_THRESH) ? (unsigned)dv.y : 8u;
            const unsigned c = (pv.z <= P_THRESH) ? (unsigned)dv.z : 8u;
            const unsigned e = (pv.w <= P_THRESH) ? (unsigned)dv.w : 8u;
            m = a | (b << 8) | (c << 16) | (e << 24);
            if (gr == 0) {              // top row: d in {0,1,2} writes up -> OOB
                unsigned mm = 0;
                #pragma unroll
                for (int i2 = 0; i2 < 4; ++i2) {
                    unsigned bb = (m >> (8 * i2)) & 255u;
                    bb = (bb <= 2u) ? 8u : bb;
                    mm |= bb << (8 * i2);
                }
                m = mm;
            } else if (gr == H - 1) {   // bottom row: d in {6,7} writes down -> OOB
                unsigned mm = 0;
                #pragma unroll
                for (int i2 = 0; i2 < 4; ++i2) {
                    unsigned bb = (m >> (8 * i2)) & 255u;
                    bb = (bb >= 6u) ? 8u : bb;
                    mm |= bb << (8 * i2);
                }
                m = mm;
            }
            if (w == 0) {               // image col 0: d in {0,3,6} (dj=-1) -> OOB
                const unsigned b0 = m & 255u;
                if ((0x49u >> b0) & 1u) m = (m & ~255u) | 8u;
            }
            if (w == 31) {              // image col 127: d in {2,5} (dj=+1) -> OOB
                const unsigned b3 = m >> 24;
                if ((0x24u >> b3) & 1u) m = (m & 0x00FFFFFFu) | (8u << 24);
            }
        } else {
            m = 0x08080808u;            // out-of-image rows never source writes
        }
        s_mk[1 + 33 * lr + w] = m;
        if (w == 31) s_mk[1 + 33 * lr + 32] = 0x08080808u;   // row pad
    } else if (tid == 320) {
        s_mk[0] = 0x08080808u;          // guard before row 0
    }
    __syncthreads();

    // ---- mask windows: bytes = cols {j0-1, j0, j0+1, j0+2}; no edge cases ----
    // byte addr of col j0-1 in LDS row rm (incl. 4B guard) = 132*rm + j0 + 3
    unsigned mrow[3];
    #pragma unroll
    for (int dr = 0; dr < 3; ++dr) {
        const int addr = 132 * (row + dr) + (j0 + 3);
        const unsigned w0 = s_mk[addr >> 2];
        const unsigned w1 = s_mk[(addr >> 2) + 1];
        const int sh = 8 * (addr & 3);           // lane even: 24, odd: 8 (never 0)
        mrow[dr] = (w0 >> sh) | (w1 << (32 - sh));
    }
    const unsigned mT = mrow[0], mM = mrow[1], mB = mrow[2];

    // ---- float windows: cols {j0-1, j0, j0+1, j0+2}; 6 cndmask/row edge fix ----
    const bool e0 = (lane == 0), e63 = (lane == 63), eE = e0 | e63;
    float vT[4], vM[4], vB[4];
    {
        // lane 0 loaded cols {0..3}, wants {1,0,1,2}; lane 63 loaded {124..127},
        // wants {125,126,127,126}; others loaded exactly {j0-1..j0+2}.
        vT[0] = eE ? iT.y : iT.x;  vT[1] = e0 ? iT.x : (e63 ? iT.z : iT.y);
        vT[2] = e0 ? iT.y : (e63 ? iT.w : iT.z);  vT[3] = eE ? iT.z : iT.w;
        vM[0] = eE ? iM.y : iM.x;  vM[1] = e0 ? iM.x : (e63 ? iM.z : iM.y);
        vM[2] = e0 ? iM.y : (e63 ? iM.w : iM.z);  vM[3] = eE ? iM.z : iM.w;
        vB[0] = eE ? iB.y : iB.x;  vB[1] = e0 ? iB.x : (e63 ? iB.z : iB.y);
        vB[2] = e0 ? iB.y : (e63 ? iB.w : iB.z);  vB[3] = eE ? iB.z : iB.w;
    }

    // ---- compute 2 px ----
    float cs[4];
    #pragma unroll
    for (int w = 0; w < 4; ++w) cs[w] = vT[w] + vM[w] + vB[w];

    nf2 res;
    #pragma unroll
    for (int p = 0; p < 2; ++p) {
        const float avg = (cs[p] + cs[p + 1] + cs[p + 2]) * (1.0f / 9.0f);
        const unsigned wT = mT >> (8 * p);   // b0=m[p] b1=m[p+1] b2=m[p+2]
        const unsigned wM = mM >> (8 * p);
        const unsigned wB = mB >> (8 * p);

        float val = vM[p + 1];   // input[i][j]
        int dl = -1;             // direction of last A-write
        // A-writes ascending d; source offset = (-di,-dj)
        if (((wB >> 16) & 255u) == 0u) { val = vB[p + 2]; dl = 0; }
        if (((wB >>  8) & 255u) == 1u) { val = vB[p + 1]; dl = 1; }
        if (( wB        & 255u) == 2u) { val = vB[p];     dl = 2; }
        if (((wM >> 16) & 255u) == 3u) { val = vM[p + 2]; dl = 3; }
        if (( wM        & 255u) == 5u) { val = vM[p];     dl = 5; }
        if (((wT >> 16) & 255u) == 6u) { val = vT[p + 2]; dl = 6; }
        if (((wT >>  8) & 255u) == 7u) { val = vT[p + 1]; dl = 7; }

        // B-write (avg): borders pre-folded -> just active + priority
        const int msel = (int)((wM >> 8) & 255u);
        if ((msel < 8) & (msel >= dl)) val = avg;
        res[p] = val;
    }
    *(nf2*)(out + base + (size_t)gi * W + j0) = res;
}

extern "C" void kernel_launch(void* const* d_in, const int* in_sizes, int n_in,
                              void* d_out, int out_size, void* d_ws, size_t ws_size,
                              hipStream_t stream) {
    const float* inp  = (const float*)d_in[0];
    const int*   dirp = (const int*)d_in[1];
    const int*   prb  = (const int*)d_in[2];
    float* out = (float*)d_out;

    const int slices = in_sizes[0] / (H * W);   // 2048
    const int grid = slices * 16;               // 8 rows per block -> 32768
    brown_kernel<<<grid, 512, 0, stream>>>(inp, dirp, prb, out);
}